// Round 5
// baseline (209.187 us; speedup 1.0000x reference)
//
#include <hip/hip_runtime.h>
#include <math.h>

#define SS 2048
#define DD 1024
#define HH 16
#define NQKV 3072
#define MROWS 4096
#define KD 1024

typedef __attribute__((ext_vector_type(8))) short bf16x8;
typedef __attribute__((ext_vector_type(8))) unsigned short us8;
typedef __attribute__((ext_vector_type(4))) float f32x4;
typedef unsigned short u16;
typedef unsigned int u32;

#define SCALE_C 0.18033688011112042f  // log2(e)/sqrt(64), folded into Q at GEMM epilogue

// async global->LDS, 16B per lane; LDS dst = wave-uniform base + lane*16
#define GLDS16(g, l) \
  __builtin_amdgcn_global_load_lds((const __attribute__((address_space(1))) u32*)(g), \
                                   (__attribute__((address_space(3))) u32*)(l), 16, 0, 0)

static __device__ __forceinline__ u16 f2bf(float f) {
  union { float f; u32 u; } v; v.f = f;
  u32 u = v.u;
  u += 0x7fffu + ((u >> 16) & 1u);   // RNE
  return (u16)(u >> 16);
}
static __device__ __forceinline__ u32 pk2(float a, float b) {      // RNE pack
  return (u32)f2bf(a) | ((u32)f2bf(b) << 16);
}
static __device__ __forceinline__ u32 pk2t(float a, float b) {     // truncating pack, 1 v_perm
  union { float f; u32 u; } ua, ub; ua.f = a; ub.f = b;
  return __builtin_amdgcn_perm(ub.u, ua.u, 0x07060302u);
}

// ---- merged prep: x convert (blocks 0..2047), w_qkv T (2048..2815), w_proj T (2816..3071) ----
__global__ __launch_bounds__(256) void k_prep(const float* __restrict__ x,
                                              const float* __restrict__ w_qkv,
                                              const float* __restrict__ w_proj,
                                              u16* __restrict__ x_bf,
                                              u16* __restrict__ wqkvT,
                                              u16* __restrict__ wprojT) {
  __shared__ float t[64][65];
  int bx = blockIdx.x;
  int tid = threadIdx.x;
  if (bx < 2048) {
    int i = (bx * 256 + tid) * 8;
    float4 a = *(const float4*)(x + i);
    float4 b = *(const float4*)(x + i + 4);
    us8 o;
    o[0] = f2bf(a.x); o[1] = f2bf(a.y); o[2] = f2bf(a.z); o[3] = f2bf(a.w);
    o[4] = f2bf(b.x); o[5] = f2bf(b.y); o[6] = f2bf(b.z); o[7] = f2bf(b.w);
    *(us8*)(x_bf + i) = o;
    return;
  }
  const float* in; u16* out; int R = KD, C, tile;
  if (bx < 2048 + 768) { in = w_qkv; out = wqkvT; C = NQKV; tile = bx - 2048; }
  else                 { in = w_proj; out = wprojT; C = DD; tile = bx - 2816; }
  int tilesC = C >> 6;
  int tc = tile % tilesC, tr = tile / tilesC;
  int r0 = tr * 64, c0 = tc * 64;
  int lx = tid & 63, ly = tid >> 6;
#pragma unroll
  for (int i = 0; i < 16; i++) {
    int rr = ly + i * 4;
    t[rr][lx] = in[(size_t)(r0 + rr) * C + c0 + lx];
  }
  __syncthreads();
#pragma unroll
  for (int i = 0; i < 16; i++) {
    int cc = ly + i * 4;
    out[(size_t)(c0 + cc) * R + r0 + lx] = f2bf(t[lx][cc]);
  }
}

// ---- bf16 GEMM, m97-class staging. BM = 128 or 64 rows per block.
// MODE 0: f32 out. MODE 2 (BM=128): bf16 qkv out; Q cols (n<1024) pre-scaled by
// SCALE_C; V cols (n>=2048) written ONLY transposed to vt[(b*16+h)*64+d][s]. ----
template <int MODE, int BM>
__global__ __launch_bounds__(256, 2) void k_gemm(const u16* __restrict__ A,
                                                 const u16* __restrict__ Bt,
                                                 const float* __restrict__ bias,
                                                 void* __restrict__ Cout,
                                                 u16* __restrict__ vt,
                                                 int M, int N, int K) {
  constexpr int MT = BM / 32;               // row-subtiles per wave: 4 or 2
  __shared__ alignas(16) u16 As[BM * 32];   // rows 64B, XOR-swizzled 16B chunks
  __shared__ alignas(16) u16 Bs[128 * 32];
  const int tid = threadIdx.x;
  const int w = tid >> 6, ln = tid & 63;
  const int wm = w >> 1, wn = w & 1;
  const int lm = ln & 15, quad = ln >> 4;
  const int m0 = blockIdx.y * BM, n0 = blockIdx.x * 128;
  const int lr = ln >> 2, c = ln & 3;
  const int cg = c ^ (lr & 3);

  f32x4 acc[MT][4];
#pragma unroll
  for (int i = 0; i < MT; i++)
#pragma unroll
    for (int j = 0; j < 4; j++) acc[i][j] = (f32x4){0.f, 0.f, 0.f, 0.f};

  const u16* gA0 = A  + (size_t)(m0 + 16 * w       + lr) * K + cg * 8;
  const u16* gA1 = A  + (size_t)(m0 + 16 * (w + 4) + lr) * K + cg * 8;  // BM=128 only
  const u16* gB0 = Bt + (size_t)(n0 + 16 * w       + lr) * K + cg * 8;
  const u16* gB1 = Bt + (size_t)(n0 + 16 * (w + 4) + lr) * K + cg * 8;
  char* lA0 = (char*)As + w * 1024;
  char* lA1 = (char*)As + (w + 4) * 1024;
  char* lB0 = (char*)Bs + w * 1024;
  char* lB1 = (char*)Bs + (w + 4) * 1024;

  for (int k0 = 0; k0 < K; k0 += 32) {
    GLDS16(gA0 + k0, lA0);
    if (BM == 128) GLDS16(gA1 + k0, lA1);
    GLDS16(gB0 + k0, lB0);
    GLDS16(gB1 + k0, lB1);
    __syncthreads();
    bf16x8 af[MT], bfr[4];
#pragma unroll
    for (int t = 0; t < MT; t++)
      af[t]  = *(const bf16x8*)((const char*)As + (wm * (MT * 16) + t * 16 + lm) * 64 + ((quad ^ (lm & 3)) * 16));
#pragma unroll
    for (int t = 0; t < 4; t++)
      bfr[t] = *(const bf16x8*)((const char*)Bs + (wn * 64 + t * 16 + lm) * 64 + ((quad ^ (lm & 3)) * 16));
#pragma unroll
    for (int mt = 0; mt < MT; mt++)
#pragma unroll
      for (int nt = 0; nt < 4; nt++)
        acc[mt][nt] = __builtin_amdgcn_mfma_f32_16x16x32_bf16(af[mt], bfr[nt], acc[mt][nt], 0, 0, 0);
    __syncthreads();
  }

  float bv[4];
#pragma unroll
  for (int nt = 0; nt < 4; nt++) bv[nt] = bias[n0 + wn * 64 + nt * 16 + lm];

  if (MODE == 2 && n0 >= 2 * DD) {
    // V tile: write transposed to vt. All rows of this tile share b.
    int b = m0 >> 11;
    int s0 = (m0 & 2047) + wm * 64;
#pragma unroll
    for (int mt = 0; mt < MT; mt++) {
      int s = s0 + mt * 16 + quad * 4;
#pragma unroll
      for (int nt = 0; nt < 4; nt++) {
        int n = n0 + wn * 64 + nt * 16 + lm;
        int bh = b * HH + ((n - 2 * DD) >> 6);
        int d = n & 63;
        uint2 v;
        v.x = pk2(acc[mt][nt][0] + bv[nt], acc[mt][nt][1] + bv[nt]);
        v.y = pk2(acc[mt][nt][2] + bv[nt], acc[mt][nt][3] + bv[nt]);
        *(uint2*)&vt[(size_t)(bh * 64 + d) * SS + s] = v;
      }
    }
    return;
  }

  const float qs = (MODE == 2 && n0 < DD) ? SCALE_C : 1.0f;  // fold softmax scale into Q
#pragma unroll
  for (int mt = 0; mt < MT; mt++) {
#pragma unroll
    for (int r = 0; r < 4; r++) {
      int row = m0 + wm * (MT * 16) + mt * 16 + quad * 4 + r;
#pragma unroll
      for (int nt = 0; nt < 4; nt++) {
        int col = n0 + wn * 64 + nt * 16 + lm;
        float v = (acc[mt][nt][r] + bv[nt]) * qs;
        if (MODE == 2) ((u16*)Cout)[(size_t)row * N + col] = f2bf(v);
        else           ((float*)Cout)[(size_t)row * N + col] = v;
      }
    }
  }
}

// ---- flash attention: block = (b,h,64 q rows), 4 waves x 16 q; grid 1024.
//      S^T orientation, exp2 directly on MFMA output (scale pre-folded into Q,
//      no max subtraction -- cancels exactly in O/l), dbuf K/V, 1 barrier/tile ----
__global__ __launch_bounds__(256, 3) void k_attn(const u16* __restrict__ qkv,
                                                 const u16* __restrict__ vt,
                                                 u16* __restrict__ attn) {
  __shared__ alignas(16) u16 Ks[2][64 * 64];    // dbuf [key][d]   16 KB
  __shared__ alignas(16) u16 Vs[2][64 * 64];    // dbuf [d][key]   16 KB
  __shared__ alignas(16) u16 Ps[4][16][72];     // per-wave P[q][key], pitch 144B, 9 KB

  const int tid = threadIdx.x;
  const int w = tid >> 6, ln = tid & 63;
  const int lm = ln & 15, quad = ln >> 4;
  const int bx = blockIdx.x;
  const int bh = bx >> 5;
  const int q0 = (bx & 31) * 64;
  const int b = bh >> 4, h = bh & 15;
  const size_t qkv_b = (size_t)b * SS * NQKV;
  const int hcol = h * 64;

  const int lr = ln >> 3, cc = ln & 7;
  const int cg = cc ^ lr;   // XOR-swizzled source chunk (row&7 == lr)

  // Q straight to registers: 2 x 16B per lane, once per block (already *SCALE_C)
  bf16x8 qf[2];
#pragma unroll
  for (int kk = 0; kk < 2; kk++)
    qf[kk] = *(const bf16x8*)(qkv + qkv_b +
               (size_t)(q0 + w * 16 + lm) * NQKV + hcol + kk * 32 + quad * 8);

  f32x4 o[4];
  float l = 0.f;
#pragma unroll
  for (int t = 0; t < 4; t++) o[t] = (f32x4){0, 0, 0, 0};

  char* psw = (char*)&Ps[w][0][0];

  // stage K/V tile 0 into buf 0
#pragma unroll
  for (int rr = 0; rr < 2; rr++) {
    int i = w + 4 * rr;
    GLDS16(qkv + qkv_b + (size_t)(8 * i + lr) * NQKV + DD + hcol + cg * 8, (char*)Ks[0] + i * 1024);
    GLDS16(vt + (size_t)(bh * 64 + 8 * i + lr) * SS + cg * 8,              (char*)Vs[0] + i * 1024);
  }

#pragma unroll 1
  for (int it = 0; it < SS / 64; it++) {
    __syncthreads();   // drains tile-it loads (issued one compute-phase ago)

    if (it + 1 < SS / 64) {
      int kv1 = (it + 1) * 64;
      char* kd = (char*)Ks[(it + 1) & 1];
      char* vd = (char*)Vs[(it + 1) & 1];
#pragma unroll
      for (int rr = 0; rr < 2; rr++) {
        int i = w + 4 * rr;
        GLDS16(qkv + qkv_b + (size_t)(kv1 + 8 * i + lr) * NQKV + DD + hcol + cg * 8, kd + i * 1024);
        GLDS16(vt + (size_t)(bh * 64 + 8 * i + lr) * SS + kv1 + cg * 8,              vd + i * 1024);
      }
    }

    const char* ksb = (const char*)Ks[it & 1];
    const char* vsb = (const char*)Vs[it & 1];

    // S^T = K · Q^T  (C: col = q = lane&15, row = key = quad*4+r (+16t))
    f32x4 s[4];
#pragma unroll
    for (int t = 0; t < 4; t++) s[t] = (f32x4){0, 0, 0, 0};
#pragma unroll
    for (int kk = 0; kk < 2; kk++)
#pragma unroll
      for (int t = 0; t < 4; t++) {
        bf16x8 kf = *(const bf16x8*)(ksb + (t * 16 + lm) * 128 + (((kk * 4 + quad) ^ (lm & 7)) * 16));
        s[t] = __builtin_amdgcn_mfma_f32_16x16x32_bf16(kf, qf[kk], s[t], 0, 0, 0);
      }

    // softmax numerator: p = 2^s (no shift -- cancels in O/l); sum + 2 shuffles
    float sum = 0.f;
    u32 pkv[4][2];
#pragma unroll
    for (int t = 0; t < 4; t++) {
      float p0 = __builtin_amdgcn_exp2f(s[t][0]);
      float p1 = __builtin_amdgcn_exp2f(s[t][1]);
      float p2 = __builtin_amdgcn_exp2f(s[t][2]);
      float p3 = __builtin_amdgcn_exp2f(s[t][3]);
      sum += (p0 + p1) + (p2 + p3);
      pkv[t][0] = pk2t(p0, p1);
      pkv[t][1] = pk2t(p2, p3);
    }
    sum += __shfl_xor(sum, 16);
    sum += __shfl_xor(sum, 32);
    l += sum;
#pragma unroll
    for (int t = 0; t < 4; t++) {
      uint2 v; v.x = pkv[t][0]; v.y = pkv[t][1];
      *(uint2*)(psw + lm * 144 + t * 32 + quad * 8) = v;
    }

    // O^T += V^T · P^T  (per-wave Ps: same-wave RAW via lgkmcnt, no barrier)
#pragma unroll
    for (int kk = 0; kk < 2; kk++) {
      bf16x8 pf = *(const bf16x8*)(psw + lm * 144 + kk * 64 + quad * 16);
#pragma unroll
      for (int t = 0; t < 4; t++) {
        bf16x8 vf = *(const bf16x8*)(vsb + (t * 16 + lm) * 128 + (((kk * 4 + quad) ^ (lm & 7)) * 16));
        o[t] = __builtin_amdgcn_mfma_f32_16x16x32_bf16(vf, pf, o[t], 0, 0, 0);
      }
    }
  }

  // normalize + store (O^T: col = q = lm; rows d = quad*4+r)
  float il = 1.0f / l;
  int row = b * SS + q0 + w * 16 + lm;
#pragma unroll
  for (int t = 0; t < 4; t++) {
    uint2 v;
    v.x = pk2(o[t][0] * il, o[t][1] * il);
    v.y = pk2(o[t][2] * il, o[t][3] * il);
    *(uint2*)&attn[(size_t)row * DD + hcol + t * 16 + quad * 4] = v;
  }
}

extern "C" void kernel_launch(void* const* d_in, const int* in_sizes, int n_in,
                              void* d_out, int out_size, void* d_ws, size_t ws_size,
                              hipStream_t stream) {
  const float* x      = (const float*)d_in[0];
  const float* w_qkv  = (const float*)d_in[1];
  const float* b_qkv  = (const float*)d_in[2];
  const float* w_proj = (const float*)d_in[3];
  const float* b_proj = (const float*)d_in[4];
  float* out = (float*)d_out;

  u16* ws     = (u16*)d_ws;
  u16* x_bf   = ws;                                  // 4M u16
  u16* wqkvT  = x_bf   + (size_t)MROWS * KD;         // 3M
  u16* wprojT = wqkvT  + (size_t)NQKV * KD;          // 1M
  u16* qkv    = wprojT + (size_t)DD * KD;            // 12M (V region unused)
  u16* attn   = qkv    + (size_t)MROWS * NQKV;       // 4M
  u16* vt     = attn   + (size_t)MROWS * DD;         // 4M

  k_prep<<<3072, 256, 0, stream>>>(x, w_qkv, w_proj, x_bf, wqkvT, wprojT);
  k_gemm<2, 128><<<dim3(NQKV / 128, MROWS / 128), 256, 0, stream>>>(x_bf, wqkvT, b_qkv, qkv, vt, MROWS, NQKV, KD);
  k_attn<<<2 * HH * (SS / 64), 256, 0, stream>>>(qkv, vt, attn);
  k_gemm<0, 64><<<dim3(DD / 128, MROWS / 64), 256, 0, stream>>>(attn, wprojT, b_proj, out, nullptr, MROWS, DD, KD);
}